// Round 7
// baseline (118.371 us; speedup 1.0000x reference)
//
#include <hip/hip_runtime.h>

#define N_NODES 50000
#define N_EDGES 800000
#define D_IN    128
#define CAP     64   // max degree ~40 for Binomial(800k, 1/50k); 64 is >15-sigma safe

#define NPART   8                                  // = # XCDs
#define PART_SZ (N_NODES / NPART)                  // 6250 (exact)
#define ECHUNK  2048                               // edges per scatter block
#define N_CHUNKS ((N_EDGES + ECHUNK - 1) / ECHUNK) // 391
#define SCT_BLOCKS (N_CHUNKS * NPART)              // 3128
#define CVT_BLOCKS ((N_NODES * 64 + 255) / 256)    // 12500

typedef float f32x2 __attribute__((ext_vector_type(2)));

// ---------------------------------------------------------------------------
// XCD-partitioned u16 bucket sort by dst + bf16-compressed, 16-deep MLP gather.
//
// Key change this round: all streaming single-use traffic (X reads, Xh writes,
// dst/src reads, sorted reads in k_agg) is NON-TEMPORAL so it doesn't evict
// the scatter's L2 working set (cnt + this XCD's 0.8 MB bucket slice) or
// k_agg's hot Xh lines. Bucket ids stored as u16 (src < 50000 < 65536).
//
// ws layout:
//   cnt      int [N_NODES]         degree/cursor (atomic)
//   sorted16 u16 [N_NODES*CAP]     src ids, segment i at i*CAP   (6.4 MB)
//   Xh       u16 [N_NODES*D_IN]    bf16(X)                       (12.8 MB)
//   selfdot  f32 [N_NODES]         W_r . x_i + b_l
// ---------------------------------------------------------------------------

__device__ __forceinline__ unsigned short f32_to_bf16_rn(float f) {
    unsigned int u = __float_as_uint(f);
    u += 0x7fffu + ((u >> 16) & 1u);      // round-to-nearest-even
    return (unsigned short)(u >> 16);
}

__global__ __launch_bounds__(256) void k_prep(
    const float* __restrict__ X,
    const float* __restrict__ W_r,
    const float* __restrict__ b_l,
    const int*   __restrict__ src,
    const int*   __restrict__ dst,
    int*         __restrict__ cnt,
    unsigned short* __restrict__ sorted16,
    unsigned short* __restrict__ Xh,
    float*       __restrict__ selfdot)
{
    int b = blockIdx.x;
    if (b < SCT_BLOCKS) {
        int part  = b & (NPART - 1);       // presumed XCD id (round-robin)
        int chunk = b >> 3;
        int lo = part * PART_SZ;
        int hi = lo + PART_SZ;
        int base = chunk * ECHUNK + threadIdx.x;
#pragma unroll
        for (int k = 0; k < ECHUNK / 256; ++k) {
            int e = base + (k << 8);
            if (e < N_EDGES) {
                int t = __builtin_nontemporal_load(&dst[e]);
                if (t >= lo && t < hi) {
                    int s = __builtin_nontemporal_load(&src[e]);
                    int p = atomicAdd(&cnt[t], 1);
                    if (p < CAP)
                        sorted16[t * CAP + p] = (unsigned short)s;
                }
            }
        }
        return;
    }
    // convert role: one wave per row -> bf16 row + selfdot = W_r.x + b_l
    int wave = ((b - SCT_BLOCKS) * 256 + threadIdx.x) >> 6;
    int lane = threadIdx.x & 63;
    if (wave >= N_NODES) return;

    const f32x2* Xr = (const f32x2*)(X + (size_t)wave * D_IN);
    f32x2 x = __builtin_nontemporal_load(&Xr[lane]);
    unsigned int packed = ((unsigned int)f32_to_bf16_rn(x.y) << 16)
                        |  (unsigned int)f32_to_bf16_rn(x.x);
    __builtin_nontemporal_store(packed,
        &((unsigned int*)Xh)[(size_t)wave * 64 + lane]);

    f32x2 wr = ((const f32x2*)W_r)[lane];
    float acc = x.x * wr.x + x.y * wr.y;
#pragma unroll
    for (int off = 32; off; off >>= 1)
        acc += __shfl_down(acc, off);
    if (lane == 0)
        selfdot[wave] = acc + b_l[0];
}

#define GATHER(mm, ss)                                                \
    {                                                                 \
        unsigned int u = Xu[(size_t)(ss) * 64 + lane];                \
        (mm).x = fmaxf((mm).x, __uint_as_float(u << 16));             \
        (mm).y = fmaxf((mm).y, __uint_as_float(u & 0xffff0000u));     \
    }
#define GBATCH(K, I)                                                  \
    {                                                                 \
        int sreg[K];                                                  \
        _Pragma("unroll")                                             \
        for (int k = 0; k < K; ++k) sreg[k] = __shfl(sid, (I) + k);   \
        _Pragma("unroll")                                             \
        for (int k = 0; k < K; ++k) GATHER(m[k], sreg[k])             \
    }

// One wave per node. Up to 16 independent gathers in flight (MLP).
__global__ __launch_bounds__(256) void k_agg(
    const unsigned short* __restrict__ Xh,
    const int*   __restrict__ cnt,
    const unsigned short* __restrict__ sorted16,
    const float* __restrict__ W_l,
    const float* __restrict__ selfdot,
    float*       __restrict__ out)
{
    int wave = (blockIdx.x * 256 + threadIdx.x) >> 6;
    int lane = threadIdx.x & 63;
    if (wave >= N_NODES) return;

    int n = cnt[wave];
    if (n > CAP) n = CAP;
    // whole segment id-list: 64 lanes x u16 = 128 B, single-use -> NT
    int sid = (lane < n)
        ? (int)__builtin_nontemporal_load(&sorted16[wave * CAP + lane]) : 0;

    f32x2 wl = ((const f32x2*)W_l)[lane];   // hoisted: overlaps gather latency
    float sd  = selfdot[wave];

    const unsigned int* Xu = (const unsigned int*)Xh;
    float2 m[16];
#pragma unroll
    for (int k = 0; k < 16; ++k) m[k] = make_float2(-INFINITY, -INFINITY);

    int i = 0;
    for (; i + 16 <= n; i += 16) GBATCH(16, i)
    if (i + 8 <= n) { GBATCH(8, i) i += 8; }
    if (i + 4 <= n) { GBATCH(4, i) i += 4; }
    if (i + 2 <= n) { GBATCH(2, i) i += 2; }
    if (i < n)      { GBATCH(1, i) }

#pragma unroll
    for (int k = 8; k; k >>= 1)
#pragma unroll
        for (int j = 0; j < k; ++j) {
            m[j].x = fmaxf(m[j].x, m[j + k].x);
            m[j].y = fmaxf(m[j].y, m[j + k].y);
        }
    if (n == 0) { m[0].x = 0.0f; m[0].y = 0.0f; }   // segment_max empty fill

    float acc = m[0].x * wl.x + m[0].y * wl.y;
#pragma unroll
    for (int off = 32; off; off >>= 1)
        acc += __shfl_down(acc, off);
    if (lane == 0)
        out[wave] = acc + sd;
}

extern "C" void kernel_launch(void* const* d_in, const int* in_sizes, int n_in,
                              void* d_out, int out_size, void* d_ws, size_t ws_size,
                              hipStream_t stream)
{
    const float* X   = (const float*)d_in[0];   // [N_NODES, D_IN]
    const float* W_l = (const float*)d_in[1];   // [1, D_IN]
    const float* b_l = (const float*)d_in[2];   // [1]
    const float* W_r = (const float*)d_in[3];   // [1, D_IN]
    const int*   ei  = (const int*)d_in[4];     // [2, N_EDGES]
    const int*   src = ei;
    const int*   dst = ei + N_EDGES;

    int* cnt = (int*)d_ws;                                   // 200 KB
    unsigned short* sorted16 = (unsigned short*)(cnt + N_NODES);      // 6.4 MB
    unsigned short* Xh = sorted16 + (size_t)N_NODES * CAP;            // 12.8 MB
    float* selfdot = (float*)(Xh + (size_t)N_NODES * D_IN);           // 200 KB
    float* out = (float*)d_out;

    hipMemsetAsync(cnt, 0, N_NODES * sizeof(int), stream);

    k_prep<<<SCT_BLOCKS + CVT_BLOCKS, 256, 0, stream>>>(
        X, W_r, b_l, src, dst, cnt, sorted16, Xh, selfdot);
    k_agg<<<(N_NODES * 64 + 255) / 256, 256, 0, stream>>>(
        Xh, cnt, sorted16, W_l, selfdot, out);
}

// Round 8
// 85.387 us; speedup vs baseline: 1.3863x; 1.3863x over previous
//
#include <hip/hip_runtime.h>

#define N_NODES 50000
#define N_EDGES 800000
#define D_IN    128
#define CAP     64   // max degree ~40 for Binomial(800k, 1/50k); 64 is >15-sigma safe

#define NPART   8                                  // = # XCDs
#define PART_SZ (N_NODES / NPART)                  // 6250 (exact)
#define ECHUNK  2048                               // edges per scatter block
#define N_CHUNKS ((N_EDGES + ECHUNK - 1) / ECHUNK) // 391
#define SCT_BLOCKS (N_CHUNKS * NPART)              // 3128
#define CVT_BLOCKS ((N_NODES * 64 + 255) / 256)    // 12500

// ---------------------------------------------------------------------------
// XCD-partitioned u16 bucket sort by dst + bf16 gather, 8-deep MLP.
// Round-5 structure (85.5 us) + u16 bucket ids ONLY. No non-temporal hints
// (round 7 showed NT Xh stores kill k_agg's L2 reuse), no 16-deep unroll
// (VGPR 40 / occupancy 46% regression).
//
// ws layout:
//   cnt      int [N_NODES]         degree/cursor (atomic)
//   sorted16 u16 [N_NODES*CAP]     src ids, segment i at i*CAP   (6.4 MB)
//   Xh       u16 [N_NODES*D_IN]    bf16(X)                       (12.8 MB)
//   selfdot  f32 [N_NODES]         W_r . x_i + b_l
// ---------------------------------------------------------------------------

__device__ __forceinline__ unsigned short f32_to_bf16_rn(float f) {
    unsigned int u = __float_as_uint(f);
    u += 0x7fffu + ((u >> 16) & 1u);      // round-to-nearest-even
    return (unsigned short)(u >> 16);
}

__global__ __launch_bounds__(256) void k_prep(
    const float* __restrict__ X,
    const float* __restrict__ W_r,
    const float* __restrict__ b_l,
    const int*   __restrict__ src,
    const int*   __restrict__ dst,
    int*         __restrict__ cnt,
    unsigned short* __restrict__ sorted16,
    unsigned short* __restrict__ Xh,
    float*       __restrict__ selfdot)
{
    int b = blockIdx.x;
    if (b < SCT_BLOCKS) {
        int part  = b & (NPART - 1);       // presumed XCD id (round-robin)
        int chunk = b >> 3;
        int lo = part * PART_SZ;
        int hi = lo + PART_SZ;
        int base = chunk * ECHUNK + threadIdx.x;
#pragma unroll
        for (int k = 0; k < ECHUNK / 256; ++k) {
            int e = base + (k << 8);
            if (e < N_EDGES) {
                int t = dst[e];
                if (t >= lo && t < hi) {
                    int p = atomicAdd(&cnt[t], 1);
                    if (p < CAP)
                        sorted16[t * CAP + p] = (unsigned short)src[e];
                }
            }
        }
        return;
    }
    // convert role: one wave per row -> bf16 row + selfdot = W_r.x + b_l
    int wave = ((b - SCT_BLOCKS) * 256 + threadIdx.x) >> 6;
    int lane = threadIdx.x & 63;
    if (wave >= N_NODES) return;

    float2 x = ((const float2*)(X + (size_t)wave * D_IN))[lane];
    unsigned int packed = ((unsigned int)f32_to_bf16_rn(x.y) << 16)
                        |  (unsigned int)f32_to_bf16_rn(x.x);
    ((unsigned int*)(Xh + (size_t)wave * D_IN))[lane] = packed;

    float2 wr = ((const float2*)W_r)[lane];
    float acc = x.x * wr.x + x.y * wr.y;
#pragma unroll
    for (int off = 32; off; off >>= 1)
        acc += __shfl_down(acc, off);
    if (lane == 0)
        selfdot[wave] = acc + b_l[0];
}

#define GATHER(mm, ss)                                                \
    {                                                                 \
        unsigned int u = Xu[(size_t)(ss) * 64 + lane];                \
        (mm).x = fmaxf((mm).x, __uint_as_float(u << 16));             \
        (mm).y = fmaxf((mm).y, __uint_as_float(u & 0xffff0000u));     \
    }

// One wave per node. 8 independent gathers in flight (MLP), 4/2/1 tail.
__global__ __launch_bounds__(256) void k_agg(
    const unsigned short* __restrict__ Xh,
    const int*   __restrict__ cnt,
    const unsigned short* __restrict__ sorted16,
    const float* __restrict__ W_l,
    const float* __restrict__ selfdot,
    float*       __restrict__ out)
{
    int wave = (blockIdx.x * 256 + threadIdx.x) >> 6;
    int lane = threadIdx.x & 63;
    if (wave >= N_NODES) return;

    int n = cnt[wave];
    if (n > CAP) n = CAP;
    // whole segment id-list: 64 lanes x u16 = 128 B, one coalesced load
    int sid = (lane < n) ? (int)sorted16[wave * CAP + lane] : 0;

    float2 wl = ((const float2*)W_l)[lane];   // hoisted: overlaps gather latency
    float sd  = selfdot[wave];

    const unsigned int* Xu = (const unsigned int*)Xh;
    float2 m[8];
#pragma unroll
    for (int k = 0; k < 8; ++k) m[k] = make_float2(-INFINITY, -INFINITY);

    int i = 0;
    for (; i + 8 <= n; i += 8) {
        int s0 = __shfl(sid, i + 0), s1 = __shfl(sid, i + 1);
        int s2 = __shfl(sid, i + 2), s3 = __shfl(sid, i + 3);
        int s4 = __shfl(sid, i + 4), s5 = __shfl(sid, i + 5);
        int s6 = __shfl(sid, i + 6), s7 = __shfl(sid, i + 7);
        GATHER(m[0], s0) GATHER(m[1], s1) GATHER(m[2], s2) GATHER(m[3], s3)
        GATHER(m[4], s4) GATHER(m[5], s5) GATHER(m[6], s6) GATHER(m[7], s7)
    }
    if (i + 4 <= n) {
        int s0 = __shfl(sid, i + 0), s1 = __shfl(sid, i + 1);
        int s2 = __shfl(sid, i + 2), s3 = __shfl(sid, i + 3);
        GATHER(m[0], s0) GATHER(m[1], s1) GATHER(m[2], s2) GATHER(m[3], s3)
        i += 4;
    }
    if (i + 2 <= n) {
        int s0 = __shfl(sid, i + 0), s1 = __shfl(sid, i + 1);
        GATHER(m[0], s0) GATHER(m[1], s1)
        i += 2;
    }
    if (i < n) {
        int s0 = __shfl(sid, i);
        GATHER(m[0], s0)
    }
#pragma unroll
    for (int k = 4; k; k >>= 1)
#pragma unroll
        for (int j = 0; j < k; ++j) {
            m[j].x = fmaxf(m[j].x, m[j + k].x);
            m[j].y = fmaxf(m[j].y, m[j + k].y);
        }
    if (n == 0) { m[0].x = 0.0f; m[0].y = 0.0f; }   // segment_max empty fill

    float acc = m[0].x * wl.x + m[0].y * wl.y;
#pragma unroll
    for (int off = 32; off; off >>= 1)
        acc += __shfl_down(acc, off);
    if (lane == 0)
        out[wave] = acc + sd;
}

extern "C" void kernel_launch(void* const* d_in, const int* in_sizes, int n_in,
                              void* d_out, int out_size, void* d_ws, size_t ws_size,
                              hipStream_t stream)
{
    const float* X   = (const float*)d_in[0];   // [N_NODES, D_IN]
    const float* W_l = (const float*)d_in[1];   // [1, D_IN]
    const float* b_l = (const float*)d_in[2];   // [1]
    const float* W_r = (const float*)d_in[3];   // [1, D_IN]
    const int*   ei  = (const int*)d_in[4];     // [2, N_EDGES]
    const int*   src = ei;
    const int*   dst = ei + N_EDGES;

    int* cnt = (int*)d_ws;                                            // 200 KB
    unsigned short* sorted16 = (unsigned short*)(cnt + N_NODES);      // 6.4 MB
    unsigned short* Xh = sorted16 + (size_t)N_NODES * CAP;            // 12.8 MB
    float* selfdot = (float*)(Xh + (size_t)N_NODES * D_IN);           // 200 KB
    float* out = (float*)d_out;

    hipMemsetAsync(cnt, 0, N_NODES * sizeof(int), stream);

    k_prep<<<SCT_BLOCKS + CVT_BLOCKS, 256, 0, stream>>>(
        X, W_r, b_l, src, dst, cnt, sorted16, Xh, selfdot);
    k_agg<<<(N_NODES * 64 + 255) / 256, 256, 0, stream>>>(
        Xh, cnt, sorted16, W_l, selfdot, out);
}

// Round 9
// 79.122 us; speedup vs baseline: 1.4961x; 1.0792x over previous
//
#include <hip/hip_runtime.h>

#define N_NODES 50000
#define N_EDGES 800000
#define D_IN    128
#define CAP     64   // max degree ~40 for Binomial(800k, 1/50k); 64 is >15-sigma safe

#define CNT_STRIDE 16  // pad each counter to its own 64B L2 line (atomic serialization fix)

#define NPART   8                                  // = # XCDs
#define PART_SZ (N_NODES / NPART)                  // 6250 (exact)
#define ECHUNK  2048                               // edges per scatter block
#define N_CHUNKS ((N_EDGES + ECHUNK - 1) / ECHUNK) // 391
#define SCT_BLOCKS (N_CHUNKS * NPART)              // 3128
#define CVT_BLOCKS ((N_NODES * 64 + 255) / 256)    // 12500

// ---------------------------------------------------------------------------
// XCD-partitioned u16 bucket sort by dst + bf16 gather, 8-deep MLP.
// Round-8 structure + line-padded counters ONLY (isolated experiment:
// same-line L2 atomic serialization hypothesis).
//
// ws layout:
//   cnt      int [N_NODES*16]      degree/cursor, 1 counter per 64B line (3.2 MB)
//   sorted16 u16 [N_NODES*CAP]     src ids, segment i at i*CAP   (6.4 MB)
//   Xh       u16 [N_NODES*D_IN]    bf16(X)                       (12.8 MB)
//   selfdot  f32 [N_NODES]         W_r . x_i + b_l
// ---------------------------------------------------------------------------

__device__ __forceinline__ unsigned short f32_to_bf16_rn(float f) {
    unsigned int u = __float_as_uint(f);
    u += 0x7fffu + ((u >> 16) & 1u);      // round-to-nearest-even
    return (unsigned short)(u >> 16);
}

__global__ __launch_bounds__(256) void k_prep(
    const float* __restrict__ X,
    const float* __restrict__ W_r,
    const float* __restrict__ b_l,
    const int*   __restrict__ src,
    const int*   __restrict__ dst,
    int*         __restrict__ cnt,
    unsigned short* __restrict__ sorted16,
    unsigned short* __restrict__ Xh,
    float*       __restrict__ selfdot)
{
    int b = blockIdx.x;
    if (b < SCT_BLOCKS) {
        int part  = b & (NPART - 1);       // presumed XCD id (round-robin)
        int chunk = b >> 3;
        int lo = part * PART_SZ;
        int hi = lo + PART_SZ;
        int base = chunk * ECHUNK + threadIdx.x;
#pragma unroll
        for (int k = 0; k < ECHUNK / 256; ++k) {
            int e = base + (k << 8);
            if (e < N_EDGES) {
                int t = dst[e];
                if (t >= lo && t < hi) {
                    int p = atomicAdd(&cnt[t * CNT_STRIDE], 1);
                    if (p < CAP)
                        sorted16[t * CAP + p] = (unsigned short)src[e];
                }
            }
        }
        return;
    }
    // convert role: one wave per row -> bf16 row + selfdot = W_r.x + b_l
    int wave = ((b - SCT_BLOCKS) * 256 + threadIdx.x) >> 6;
    int lane = threadIdx.x & 63;
    if (wave >= N_NODES) return;

    float2 x = ((const float2*)(X + (size_t)wave * D_IN))[lane];
    unsigned int packed = ((unsigned int)f32_to_bf16_rn(x.y) << 16)
                        |  (unsigned int)f32_to_bf16_rn(x.x);
    ((unsigned int*)(Xh + (size_t)wave * D_IN))[lane] = packed;

    float2 wr = ((const float2*)W_r)[lane];
    float acc = x.x * wr.x + x.y * wr.y;
#pragma unroll
    for (int off = 32; off; off >>= 1)
        acc += __shfl_down(acc, off);
    if (lane == 0)
        selfdot[wave] = acc + b_l[0];
}

#define GATHER(mm, ss)                                                \
    {                                                                 \
        unsigned int u = Xu[(size_t)(ss) * 64 + lane];                \
        (mm).x = fmaxf((mm).x, __uint_as_float(u << 16));             \
        (mm).y = fmaxf((mm).y, __uint_as_float(u & 0xffff0000u));     \
    }

// One wave per node. 8 independent gathers in flight (MLP), 4/2/1 tail.
__global__ __launch_bounds__(256) void k_agg(
    const unsigned short* __restrict__ Xh,
    const int*   __restrict__ cnt,
    const unsigned short* __restrict__ sorted16,
    const float* __restrict__ W_l,
    const float* __restrict__ selfdot,
    float*       __restrict__ out)
{
    int wave = (blockIdx.x * 256 + threadIdx.x) >> 6;
    int lane = threadIdx.x & 63;
    if (wave >= N_NODES) return;

    int n = cnt[wave * CNT_STRIDE];
    if (n > CAP) n = CAP;
    // whole segment id-list: 64 lanes x u16 = 128 B, one coalesced load
    int sid = (lane < n) ? (int)sorted16[wave * CAP + lane] : 0;

    float2 wl = ((const float2*)W_l)[lane];   // hoisted: overlaps gather latency
    float sd  = selfdot[wave];

    const unsigned int* Xu = (const unsigned int*)Xh;
    float2 m[8];
#pragma unroll
    for (int k = 0; k < 8; ++k) m[k] = make_float2(-INFINITY, -INFINITY);

    int i = 0;
    for (; i + 8 <= n; i += 8) {
        int s0 = __shfl(sid, i + 0), s1 = __shfl(sid, i + 1);
        int s2 = __shfl(sid, i + 2), s3 = __shfl(sid, i + 3);
        int s4 = __shfl(sid, i + 4), s5 = __shfl(sid, i + 5);
        int s6 = __shfl(sid, i + 6), s7 = __shfl(sid, i + 7);
        GATHER(m[0], s0) GATHER(m[1], s1) GATHER(m[2], s2) GATHER(m[3], s3)
        GATHER(m[4], s4) GATHER(m[5], s5) GATHER(m[6], s6) GATHER(m[7], s7)
    }
    if (i + 4 <= n) {
        int s0 = __shfl(sid, i + 0), s1 = __shfl(sid, i + 1);
        int s2 = __shfl(sid, i + 2), s3 = __shfl(sid, i + 3);
        GATHER(m[0], s0) GATHER(m[1], s1) GATHER(m[2], s2) GATHER(m[3], s3)
        i += 4;
    }
    if (i + 2 <= n) {
        int s0 = __shfl(sid, i + 0), s1 = __shfl(sid, i + 1);
        GATHER(m[0], s0) GATHER(m[1], s1)
        i += 2;
    }
    if (i < n) {
        int s0 = __shfl(sid, i);
        GATHER(m[0], s0)
    }
#pragma unroll
    for (int k = 4; k; k >>= 1)
#pragma unroll
        for (int j = 0; j < k; ++j) {
            m[j].x = fmaxf(m[j].x, m[j + k].x);
            m[j].y = fmaxf(m[j].y, m[j + k].y);
        }
    if (n == 0) { m[0].x = 0.0f; m[0].y = 0.0f; }   // segment_max empty fill

    float acc = m[0].x * wl.x + m[0].y * wl.y;
#pragma unroll
    for (int off = 32; off; off >>= 1)
        acc += __shfl_down(acc, off);
    if (lane == 0)
        out[wave] = acc + sd;
}

extern "C" void kernel_launch(void* const* d_in, const int* in_sizes, int n_in,
                              void* d_out, int out_size, void* d_ws, size_t ws_size,
                              hipStream_t stream)
{
    const float* X   = (const float*)d_in[0];   // [N_NODES, D_IN]
    const float* W_l = (const float*)d_in[1];   // [1, D_IN]
    const float* b_l = (const float*)d_in[2];   // [1]
    const float* W_r = (const float*)d_in[3];   // [1, D_IN]
    const int*   ei  = (const int*)d_in[4];     // [2, N_EDGES]
    const int*   src = ei;
    const int*   dst = ei + N_EDGES;

    int* cnt = (int*)d_ws;                                                  // 3.2 MB
    unsigned short* sorted16 = (unsigned short*)(cnt + (size_t)N_NODES * CNT_STRIDE); // 6.4 MB
    unsigned short* Xh = sorted16 + (size_t)N_NODES * CAP;                  // 12.8 MB
    float* selfdot = (float*)(Xh + (size_t)N_NODES * D_IN);                 // 200 KB
    float* out = (float*)d_out;

    hipMemsetAsync(cnt, 0, (size_t)N_NODES * CNT_STRIDE * sizeof(int), stream);

    k_prep<<<SCT_BLOCKS + CVT_BLOCKS, 256, 0, stream>>>(
        X, W_r, b_l, src, dst, cnt, sorted16, Xh, selfdot);
    k_agg<<<(N_NODES * 64 + 255) / 256, 256, 0, stream>>>(
        Xh, cnt, sorted16, W_l, selfdot, out);
}